// Round 4
// baseline (650.317 us; speedup 1.0000x reference)
//
#include <hip/hip_runtime.h>

// STGAN fused forward for MI355X. Shapes fixed per reference.
constexpr int cB = 4, cT = 24, cN = 10000, cF = 64, cE = 160000, cHID = 128, cK = 3;

typedef short s16x4 __attribute__((ext_vector_type(4)));
typedef short s16x8 __attribute__((ext_vector_type(8)));
typedef float f32x16 __attribute__((ext_vector_type(16)));

__device__ __forceinline__ unsigned short f2bf(float f) {   // RNE (one-time paths)
    union { float f; unsigned u; } c; c.f = f;
    unsigned u = c.u;
    return (unsigned short)((u + 0x7FFFu + ((u >> 16) & 1u)) >> 16);
}
__device__ __forceinline__ unsigned short f2bf_rtz(float f) {
    union { float f; unsigned u; } c; c.f = f;
    return (unsigned short)(c.u >> 16);
}
__device__ __forceinline__ unsigned asu(float f) {
    union { float f; unsigned u; } c; c.f = f; return c.u;
}

__device__ __forceinline__ float tanh_fast(float x) {
    float e = __expf(2.0f * x);
    return 1.0f - 2.0f * __builtin_amdgcn_rcpf(e + 1.0f);
}

// ---------- edge dtype detection (int32 vs int64 pushed buffer) ----------
__global__ void k_zero(int* c) { *c = 0; }

__global__ void k_detect(const int* __restrict__ edges, int* __restrict__ cnt) {
    int i = blockIdx.x * 256 + threadIdx.x;
    int z = (i < cE && edges[2 * i + 1] == 0) ? 1 : 0;
    __shared__ int sc;
    if (threadIdx.x == 0) sc = 0;
    __syncthreads();
    if (z) atomicAdd(&sc, 1);
    __syncthreads();
    if (threadIdx.x == 0 && sc) atomicAdd(cnt, sc);
}

__global__ void k_flag(const int* __restrict__ cnt, int* __restrict__ flag) {
    *flag = (*cnt > cE - 100) ? 2 : 1;
}

// zero cnt_in + cursor without a captured memset node
__global__ void k_zero2(int* __restrict__ a, int* __restrict__ b) {
    int i = blockIdx.x * 256 + threadIdx.x;
    if (i < cN) { a[i] = 0; b[i] = 0; }
}

// ---------- W1 pre-transpose: W1T[hid][gp] = bf16(W1[gp][hid]) ----------
__global__ void k_w1t(const float* __restrict__ W1, unsigned short* __restrict__ W1T) {
    __shared__ float sT[64][65];
    const int gx = blockIdx.x * 64;   // gp tile (24)
    const int hx = blockIdx.y * 64;   // hid tile (2)
    const int tid = threadIdx.x;
    #pragma unroll
    for (int r = 0; r < 4; r++) {
        int flat = tid + r * 256;             // float4 idx 0..1023
        int gp = flat >> 4, h4 = (flat & 15) * 4;
        float4 v = *(const float4*)&W1[(size_t)(gx + gp) * cHID + hx + h4];
        sT[h4 + 0][gp] = v.x; sT[h4 + 1][gp] = v.y;
        sT[h4 + 2][gp] = v.z; sT[h4 + 3][gp] = v.w;
    }
    __syncthreads();
    #pragma unroll
    for (int r = 0; r < 2; r++) {
        int flat = tid + r * 256;             // bf16x8 idx 0..511
        int h = flat >> 3, seg = flat & 7;
        s16x8 o;
        #pragma unroll
        for (int i = 0; i < 8; i++) o[i] = (short)f2bf(sT[h][seg * 8 + i]);
        *(s16x8*)&W1T[(size_t)(hx + h) * (cT * 64) + gx + seg * 8] = o;
    }
}

// ---------- hor_ctx = mean(horizon,1) @ W_hor + b_enc ----------
__global__ void k_hc(const float* __restrict__ horizon, const float* __restrict__ W_hor,
                     const float* __restrict__ b_enc, float* __restrict__ hc) {
    int g = threadIdx.x & 63;
    int sub = threadIdx.x >> 6;
    int pair = blockIdx.x * 4 + sub;          // b*N + n
    __shared__ float sm[4][64];
    bool ok = pair < cB * cN;
    float m = 0.f;
    if (ok) {
        int b = pair / cN, n = pair % cN;
        const float* hp = horizon + ((size_t)(b * 6) * cN + n) * 64 + g;
        #pragma unroll
        for (int hh = 0; hh < 6; hh++) m += hp[(size_t)hh * cN * 64];
        m *= (1.0f / 6.0f);
    }
    sm[sub][g] = m;
    __syncthreads();
    if (!ok) return;
    float a = b_enc[g];
    for (int f = 0; f < 64; f++) a = fmaf(sm[sub][f], W_hor[f * 64 + g], a);
    hc[(size_t)pair * 64 + g] = a;
}

// ---------- fused encode + MLP accumulate, bf16 MFMA, T split in halves ----------
// grid (157, B, 2); 4 waves / 64-node tile; 16 KB LDS; W1T frags direct from L2.
__launch_bounds__(256, 4)
__global__ void k_encode_mlp(const float* __restrict__ history,
                             const float* __restrict__ W_enc,
                             const float* __restrict__ hc,
                             const unsigned short* __restrict__ W1T,
                             float* __restrict__ accbuf,
                             float* __restrict__ h0) {
    __shared__ unsigned short sHist[64 * 64];   // [node][f], xor-swizzled, 8KB
    __shared__ unsigned short sXe[64 * 64];     // [node][g], xor-swizzled, 8KB
    const int tid = threadIdx.x;
    const int lane = tid & 63;
    const int w = tid >> 6;
    const int l31 = lane & 31;
    const int lhi = lane >> 5;
    const int n0 = blockIdx.x * 64;
    const int b = blockIdx.y;
    const int half = blockIdx.z;
    const int t0 = half * (cT / 2), t1 = t0 + (cT / 2);
    const int nn = min(64, cN - n0);
    const int mtile = w & 1;
    const int gtile = w >> 1;

    // W_enc B-fragments, register resident (col = gtile*32 + l31)
    s16x8 wenc[4];
    {
        int col = gtile * 32 + l31;
        #pragma unroll
        for (int ks = 0; ks < 4; ks++)
            #pragma unroll
            for (int i = 0; i < 8; i++)
                wenc[ks][i] = (short)f2bf(W_enc[(ks * 16 + lhi * 8 + i) * 64 + col]);
    }
    // hc as loop-invariant C-init
    float hcr[16];
    {
        int col = gtile * 32 + l31;
        #pragma unroll
        for (int reg = 0; reg < 16; reg++) {
            int row = mtile * 32 + (reg & 3) + 8 * (reg >> 2) + 4 * lhi;
            hcr[reg] = (row < nn) ? hc[(size_t)(b * cN + n0 + row) * 64 + col] : 0.f;
        }
    }
    f32x16 accm[2];
    #pragma unroll
    for (int nt = 0; nt < 2; nt++)
        #pragma unroll
        for (int r = 0; r < 16; r++) accm[nt][r] = 0.f;

    for (int t = t0; t < t1; t++) {
        __syncthreads();   // prev readers of sHist (encode) and sXe (MLP) done
        {   // stage hist tile fp32->bf16 (RTZ via v_perm), swizzled
            const float* hsrc = history + ((size_t)(b * cT + t) * cN + n0) * 64;
            #pragma unroll
            for (int r = 0; r < 4; r++) {
                int flat = tid + r * 256;       // float4 idx
                int node = flat >> 4, fq = flat & 15;
                float4 v = make_float4(0.f, 0.f, 0.f, 0.f);
                if (node < nn) v = *(const float4*)(hsrc + node * 64 + fq * 4);
                int2 p;
                p.x = (int)__builtin_amdgcn_perm(asu(v.y), asu(v.x), 0x07060302u);
                p.y = (int)__builtin_amdgcn_perm(asu(v.w), asu(v.z), 0x07060302u);
                int idx = (node * 64 + fq * 4) ^ ((node & 7) << 3);
                *(int2*)&sHist[idx] = p;
            }
        }
        __syncthreads();
        // encode MFMA: D[node][g], C-init = hc
        f32x16 d;
        #pragma unroll
        for (int reg = 0; reg < 16; reg++) d[reg] = hcr[reg];
        {
            int node = mtile * 32 + l31;
            int base = node * 64 + lhi * 8;
            int sw = (node & 7) << 3;
            #pragma unroll
            for (int ks = 0; ks < 4; ks++) {
                s16x8 a = *(const s16x8*)&sHist[(base + ks * 16) ^ sw];
                d = __builtin_amdgcn_mfma_f32_32x32x16_bf16(a, wenc[ks], d, 0, 0, 0);
            }
        }
        if (t == cT - 1) {
            int col = gtile * 32 + l31;
            #pragma unroll
            for (int reg = 0; reg < 16; reg++) {
                int row = mtile * 32 + (reg & 3) + 8 * (reg >> 2) + 4 * lhi;
                if (row < nn)
                    h0[(size_t)(b * cN + n0 + row) * 64 + col] = tanh_fast(d[reg]);
            }
        } else {
            int col = gtile * 32 + l31;
            #pragma unroll
            for (int reg = 0; reg < 16; reg++) {
                int row = mtile * 32 + (reg & 3) + 8 * (reg >> 2) + 4 * lhi;
                int idx = (row * 64 + col) ^ ((row & 7) << 3);
                sXe[idx] = f2bf_rtz(tanh_fast(d[reg]));
            }
            __syncthreads();   // sXe complete
            // A-fragments of W1T straight from L2 (384 KB, fully cached)
            const int hidrow = w * 32 + l31;
            const unsigned short* wrow = W1T + (size_t)hidrow * (cT * 64) + t * 64 + lhi * 8;
            s16x8 aw[4];
            #pragma unroll
            for (int ks = 0; ks < 4; ks++) aw[ks] = *(const s16x8*)(wrow + ks * 16);
            #pragma unroll
            for (int nt = 0; nt < 2; nt++) {
                int noderow = nt * 32 + l31;
                int bbase = noderow * 64 + lhi * 8;
                int swB = (noderow & 7) << 3;
                #pragma unroll
                for (int ks = 0; ks < 4; ks++) {
                    s16x8 bx = *(const s16x8*)&sXe[(bbase + ks * 16) ^ swB];
                    accm[nt] = __builtin_amdgcn_mfma_f32_32x32x16_bf16(aw[ks], bx, accm[nt], 0, 0, 0);
                }
            }
        }
    }
    // store acc' partial: lane holds node = nt*32+l31, hid quads; halves disjoint buffers
    float* abase = accbuf + (size_t)half * cB * cN * cHID;
    #pragma unroll
    for (int nt = 0; nt < 2; nt++) {
        int node = nt * 32 + l31;
        if (node < nn) {
            float* ap = abase + (size_t)(b * cN + n0 + node) * cHID;
            #pragma unroll
            for (int q = 0; q < 4; q++) {
                int hid0 = w * 32 + q * 8 + lhi * 4;
                float4 v = make_float4(accm[nt][q * 4 + 0], accm[nt][q * 4 + 1],
                                       accm[nt][q * 4 + 2], accm[nt][q * 4 + 3]);
                *(float4*)(ap + hid0) = v;
            }
        }
    }
}

// ---------- CSR build (by destination / col) ----------
__global__ void k_count(const int* __restrict__ edges, const int* __restrict__ flag,
                        int* __restrict__ cnt_in) {
    int e = blockIdx.x * 256 + threadIdx.x;
    if (e < cE) {
        int m = *flag;
        atomicAdd(&cnt_in[edges[m * (cE + e)]], 1);
    }
}

__global__ void k_dinv(const int* __restrict__ cnt_in, float* __restrict__ dinv) {
    int n = blockIdx.x * 256 + threadIdx.x;
    if (n < cN) dinv[n] = rsqrtf((float)(cnt_in[n] + 1));   // +1 self-loop
}

__global__ void k_scan(const int* __restrict__ cnt_in, int* __restrict__ rowptr) {
    __shared__ int sdata[1024];
    __shared__ int carry;
    if (threadIdx.x == 0) carry = 0;
    __syncthreads();
    for (int base = 0; base < cN; base += 1024) {
        int i = base + threadIdx.x;
        int v = (i < cN) ? cnt_in[i] : 0;
        sdata[threadIdx.x] = v;
        __syncthreads();
        for (int off = 1; off < 1024; off <<= 1) {
            int t = (threadIdx.x >= off) ? sdata[threadIdx.x - off] : 0;
            __syncthreads();
            sdata[threadIdx.x] += t;
            __syncthreads();
        }
        if (i < cN) rowptr[i] = carry + sdata[threadIdx.x] - v;   // exclusive
        __syncthreads();
        if (threadIdx.x == 1023) carry += sdata[1023];
        __syncthreads();
    }
    if (threadIdx.x == 0) rowptr[cN] = carry;
}

__global__ void k_fill(const int* __restrict__ edges, const int* __restrict__ flag,
                       const int* __restrict__ rowptr, int* __restrict__ cursor,
                       int* __restrict__ csr_src) {
    int e = blockIdx.x * 256 + threadIdx.x;
    if (e < cE) {
        int m = *flag;
        int r = edges[m * e];
        int c = edges[m * (cE + e)];
        int pos = atomicAdd(&cursor[c], 1);
        csr_src[rowptr[c] + pos] = r;
    }
}

// ---------- GCN step ----------
// xfc[n][b][g] = dinv[n] * (h[b,n,:] @ W_fc)[g]
__global__ void k_fc(const float* __restrict__ h, const float* __restrict__ W_fc,
                     const float* __restrict__ dinv, float* __restrict__ xfc) {
    int n = blockIdx.x;
    int g = threadIdx.x & 63, bb = threadIdx.x >> 6;
    __shared__ float sh[4][64];
    sh[bb][g] = h[(size_t)(bb * cN + n) * 64 + g];
    __syncthreads();
    float a = 0.f;
    #pragma unroll 8
    for (int f = 0; f < 64; f++) a = fmaf(sh[bb][f], W_fc[f * 64 + g], a);
    xfc[(size_t)n * 256 + bb * 64 + g] = dinv[n] * a;
}

// hnext[b,n,:] = b_gcn + dinv[n]*(xfc[n] + sum_in xfc[s]); wave = (node, batch-pair)
__launch_bounds__(256)
__global__ void k_gather(const int* __restrict__ rowptr, const int* __restrict__ csr_src,
                         const float* __restrict__ dinv, const float* __restrict__ xfc,
                         const float* __restrict__ b_gcn, float* __restrict__ hnext) {
    int wv = threadIdx.x >> 6;
    int n = blockIdx.x * 2 + (wv >> 1);
    if (n >= cN) return;
    int bp = wv & 1;                      // batches {0,1} or {2,3}
    int g = threadIdx.x & 63;
    const float* xn = xfc + (size_t)n * 256 + bp * 128;
    float a0 = xn[g], a1 = xn[64 + g];
    int i = rowptr[n], end = rowptr[n + 1];
    int s_next = (i < end) ? csr_src[i] : 0;
    while (i < end) {
        const float* xs = xfc + (size_t)s_next * 256 + bp * 128;
        ++i;
        s_next = (i < end) ? csr_src[i] : 0;
        a0 += xs[g]; a1 += xs[64 + g];
    }
    float di = dinv[n], bg = b_gcn[g];
    hnext[(size_t)((bp * 2 + 0) * cN + n) * 64 + g] = fmaf(di, a0, bg);
    hnext[(size_t)((bp * 2 + 1) * cN + n) * 64 + g] = fmaf(di, a1, bg);
}

// ---------- head: out = relu(acc0 + acc1 + h_fin@W1_{T-1} + b1) @ W2 + b2 ----------
__global__ void k_head(const float* __restrict__ accbuf, const float* __restrict__ hfin,
                       const float* __restrict__ W1, const float* __restrict__ b1,
                       const float* __restrict__ W2, const float* __restrict__ b2,
                       float* __restrict__ out) {
    int pair = blockIdx.x;
    int j = threadIdx.x;   // 0..127
    __shared__ float sh[64];
    __shared__ float red[128];
    if (j < 64) sh[j] = hfin[(size_t)pair * 64 + j];
    __syncthreads();
    float a = accbuf[(size_t)pair * cHID + j]
            + accbuf[(size_t)cB * cN * cHID + (size_t)pair * cHID + j] + b1[j];
    const float* wp = W1 + (size_t)(cT - 1) * 64 * cHID + j;
    for (int f = 0; f < 64; f++) a = fmaf(sh[f], wp[f * cHID], a);
    a = fmaxf(a, 0.f) * W2[j];
    red[j] = a;
    __syncthreads();
    for (int s = 64; s > 0; s >>= 1) {
        if (j < s) red[j] += red[j + s];
        __syncthreads();
    }
    if (j == 0) out[pair] = red[0] + b2[0];
}

extern "C" void kernel_launch(void* const* d_in, const int* in_sizes, int n_in,
                              void* d_out, int out_size, void* d_ws, size_t ws_size,
                              hipStream_t stream) {
    const float* history = (const float*)d_in[0];
    const float* horizon = (const float*)d_in[1];
    const int*   edges   = (const int*)d_in[2];
    const float* W_enc   = (const float*)d_in[3];
    const float* W_hor   = (const float*)d_in[4];
    const float* b_enc   = (const float*)d_in[5];
    const float* W_fc    = (const float*)d_in[6];
    const float* b_gcn   = (const float*)d_in[7];
    const float* W1      = (const float*)d_in[8];
    const float* b1      = (const float*)d_in[9];
    const float* W2      = (const float*)d_in[10];
    const float* b2      = (const float*)d_in[11];
    float* out = (float*)d_out;

    float* ws = (float*)d_ws;
    float* hc     = ws;                                   // B*N*64
    float* accbuf = hc + (size_t)cB * cN * 64;            // 2 * B*N*128 (two halves)
    float* h0     = accbuf + (size_t)2 * cB * cN * cHID;  // B*N*64
    float* h1     = h0 + (size_t)cB * cN * 64;            // B*N*64
    float* xfc    = h1 + (size_t)cB * cN * 64;            // N*B*64 (n-major)
    float* dinv   = xfc + (size_t)cB * cN * 64;           // N
    unsigned short* w1t = (unsigned short*)(dinv + cN);   // 128*1536 bf16
    int*   cnt_in = (int*)(w1t + (size_t)cHID * cT * 64); // N
    int*   cursor = cnt_in + cN;                          // N
    int*   rowptr = cursor + cN;                          // N+1
    int*   csr_src= rowptr + cN + 1;                      // E
    int*   cnt    = csr_src + cE;
    int*   flag   = cnt + 1;

    k_zero<<<1, 1, 0, stream>>>(cnt);
    k_detect<<<(cE + 255) / 256, 256, 0, stream>>>(edges, cnt);
    k_flag<<<1, 1, 0, stream>>>(cnt, flag);

    k_w1t<<<dim3(cT * 64 / 64, cHID / 64), 256, 0, stream>>>(W1, w1t);
    k_hc<<<(cB * cN + 3) / 4, 256, 0, stream>>>(horizon, W_hor, b_enc, hc);
    k_encode_mlp<<<dim3((cN + 63) / 64, cB, 2), 256, 0, stream>>>(history, W_enc, hc, w1t, accbuf, h0);

    k_zero2<<<(cN + 255) / 256, 256, 0, stream>>>(cnt_in, cursor);
    k_count<<<(cE + 255) / 256, 256, 0, stream>>>(edges, flag, cnt_in);
    k_dinv<<<(cN + 255) / 256, 256, 0, stream>>>(cnt_in, dinv);
    k_scan<<<1, 1024, 0, stream>>>(cnt_in, rowptr);
    k_fill<<<(cE + 255) / 256, 256, 0, stream>>>(edges, flag, rowptr, cursor, csr_src);

    float* hin = h0; float* hout = h1;
    for (int s = 0; s < cK; s++) {
        k_fc<<<cN, 256, 0, stream>>>(hin, W_fc, dinv, xfc);
        k_gather<<<(cN + 1) / 2, 256, 0, stream>>>(rowptr, csr_src, dinv, xfc, b_gcn, hout);
        float* tmp = hin; hin = hout; hout = tmp;
    }

    k_head<<<cB * cN, 128, 0, stream>>>(accbuf, hin, W1, b1, W2, b2, out);
}

// Round 5
// 647.239 us; speedup vs baseline: 1.0048x; 1.0048x over previous
//
#include <hip/hip_runtime.h>

// STGAN fused forward for MI355X. Shapes fixed per reference.
constexpr int cB = 4, cT = 24, cN = 10000, cF = 64, cE = 160000, cHID = 128, cK = 3;

typedef short s16x4 __attribute__((ext_vector_type(4)));
typedef short s16x8 __attribute__((ext_vector_type(8)));
typedef float f32x16 __attribute__((ext_vector_type(16)));

__device__ __forceinline__ unsigned short f2bf(float f) {   // RNE (one-time paths)
    union { float f; unsigned u; } c; c.f = f;
    unsigned u = c.u;
    return (unsigned short)((u + 0x7FFFu + ((u >> 16) & 1u)) >> 16);
}
__device__ __forceinline__ unsigned short f2bf_rtz(float f) {
    union { float f; unsigned u; } c; c.f = f;
    return (unsigned short)(c.u >> 16);
}
__device__ __forceinline__ unsigned asu(float f) {
    union { float f; unsigned u; } c; c.f = f; return c.u;
}

__device__ __forceinline__ float tanh_fast(float x) {
    float e = __expf(2.0f * x);
    return 1.0f - 2.0f * __builtin_amdgcn_rcpf(e + 1.0f);
}

// ---------- edge dtype detection (int32 vs int64 pushed buffer) ----------
__global__ void k_zero(int* c) { *c = 0; }

__global__ void k_detect(const int* __restrict__ edges, int* __restrict__ cnt) {
    int i = blockIdx.x * 256 + threadIdx.x;
    int z = (i < cE && edges[2 * i + 1] == 0) ? 1 : 0;
    __shared__ int sc;
    if (threadIdx.x == 0) sc = 0;
    __syncthreads();
    if (z) atomicAdd(&sc, 1);
    __syncthreads();
    if (threadIdx.x == 0 && sc) atomicAdd(cnt, sc);
}

__global__ void k_flag(const int* __restrict__ cnt, int* __restrict__ flag) {
    *flag = (*cnt > cE - 100) ? 2 : 1;
}

// zero cnt_in + cursor without a captured memset node
__global__ void k_zero2(int* __restrict__ a, int* __restrict__ b) {
    int i = blockIdx.x * 256 + threadIdx.x;
    if (i < cN) { a[i] = 0; b[i] = 0; }
}

// ---------- W1 pre-transpose: W1T[hid][gp] = bf16(W1[gp][hid]) ----------
__global__ void k_w1t(const float* __restrict__ W1, unsigned short* __restrict__ W1T) {
    __shared__ float sT[64][65];
    const int gx = blockIdx.x * 64;   // gp tile (24)
    const int hx = blockIdx.y * 64;   // hid tile (2)
    const int tid = threadIdx.x;
    #pragma unroll
    for (int r = 0; r < 4; r++) {
        int flat = tid + r * 256;             // float4 idx 0..1023
        int gp = flat >> 4, h4 = (flat & 15) * 4;
        float4 v = *(const float4*)&W1[(size_t)(gx + gp) * cHID + hx + h4];
        sT[h4 + 0][gp] = v.x; sT[h4 + 1][gp] = v.y;
        sT[h4 + 2][gp] = v.z; sT[h4 + 3][gp] = v.w;
    }
    __syncthreads();
    #pragma unroll
    for (int r = 0; r < 2; r++) {
        int flat = tid + r * 256;             // bf16x8 idx 0..511
        int h = flat >> 3, seg = flat & 7;
        s16x8 o;
        #pragma unroll
        for (int i = 0; i < 8; i++) o[i] = (short)f2bf(sT[h][seg * 8 + i]);
        *(s16x8*)&W1T[(size_t)(hx + h) * (cT * 64) + gx + seg * 8] = o;
    }
}

// ---------- hor_ctx = mean(horizon,1) @ W_hor + b_enc ----------
__global__ void k_hc(const float* __restrict__ horizon, const float* __restrict__ W_hor,
                     const float* __restrict__ b_enc, float* __restrict__ hc) {
    int g = threadIdx.x & 63;
    int sub = threadIdx.x >> 6;
    int pair = blockIdx.x * 4 + sub;          // b*N + n
    __shared__ float sm[4][64];
    bool ok = pair < cB * cN;
    float m = 0.f;
    if (ok) {
        int b = pair / cN, n = pair % cN;
        const float* hp = horizon + ((size_t)(b * 6) * cN + n) * 64 + g;
        #pragma unroll
        for (int hh = 0; hh < 6; hh++) m += hp[(size_t)hh * cN * 64];
        m *= (1.0f / 6.0f);
    }
    sm[sub][g] = m;
    __syncthreads();
    if (!ok) return;
    float a = b_enc[g];
    for (int f = 0; f < 64; f++) a = fmaf(sm[sub][f], W_hor[f * 64 + g], a);
    hc[(size_t)pair * 64 + g] = a;
}

// ---------- fused encode + MLP accumulate, bf16 MFMA, software-pipelined ----------
// grid (157, B); 4 waves / 64-node tile; 16 KB LDS; next-t history loads issued
// at iteration top (consumed into LDS after the mid barrier); W1T frags from L2.
__launch_bounds__(256, 3)
__global__ void k_encode_mlp(const float* __restrict__ history,
                             const float* __restrict__ W_enc,
                             const float* __restrict__ hc,
                             const unsigned short* __restrict__ W1T,
                             float* __restrict__ accbuf,
                             float* __restrict__ h0) {
    __shared__ unsigned short sHist[64 * 64];   // [node][f], xor-swizzled, 8KB
    __shared__ unsigned short sXe[64 * 64];     // [node][g], xor-swizzled, 8KB
    const int tid = threadIdx.x;
    const int lane = tid & 63;
    const int w = tid >> 6;
    const int l31 = lane & 31;
    const int lhi = lane >> 5;
    const int n0 = blockIdx.x * 64;
    const int b = blockIdx.y;
    const int nn = min(64, cN - n0);
    const int mtile = w & 1;
    const int gtile = w >> 1;

    // per-thread staging coords (flat = tid + q*256 -> node, fq)
    float4 r[4];
    auto RLOAD = [&](int t) {
        const float* hsrc = history + ((size_t)(b * cT + t) * cN + n0) * 64;
        #pragma unroll
        for (int q = 0; q < 4; q++) {
            int flat = tid + q * 256;
            int node = flat >> 4, fq = flat & 15;
            r[q] = make_float4(0.f, 0.f, 0.f, 0.f);
            if (node < nn) r[q] = *(const float4*)(hsrc + node * 64 + fq * 4);
        }
    };
    auto SSTORE = [&]() {
        #pragma unroll
        for (int q = 0; q < 4; q++) {
            int flat = tid + q * 256;
            int node = flat >> 4, fq = flat & 15;
            int2 p;
            p.x = (int)__builtin_amdgcn_perm(asu(r[q].y), asu(r[q].x), 0x07060302u);
            p.y = (int)__builtin_amdgcn_perm(asu(r[q].w), asu(r[q].z), 0x07060302u);
            int idx = (node * 64 + fq * 4) ^ ((node & 7) << 3);
            *(int2*)&sHist[idx] = p;
        }
    };

    // W_enc B-fragments, register resident (col = gtile*32 + l31)
    s16x8 wenc[4];
    {
        int col = gtile * 32 + l31;
        #pragma unroll
        for (int ks = 0; ks < 4; ks++)
            #pragma unroll
            for (int i = 0; i < 8; i++)
                wenc[ks][i] = (short)f2bf(W_enc[(ks * 16 + lhi * 8 + i) * 64 + col]);
    }
    // hc as loop-invariant C-init
    float hcr[16];
    {
        int col = gtile * 32 + l31;
        #pragma unroll
        for (int reg = 0; reg < 16; reg++) {
            int row = mtile * 32 + (reg & 3) + 8 * (reg >> 2) + 4 * lhi;
            hcr[reg] = (row < nn) ? hc[(size_t)(b * cN + n0 + row) * 64 + col] : 0.f;
        }
    }
    f32x16 accm[2];
    #pragma unroll
    for (int nt = 0; nt < 2; nt++)
        #pragma unroll
        for (int rr = 0; rr < 16; rr++) accm[nt][rr] = 0.f;

    RLOAD(0);
    SSTORE();
    __syncthreads();

    for (int t = 0; t < cT; t++) {
        const bool last = (t == cT - 1);
        if (!last) RLOAD(t + 1);            // issue early; consumed after mid barrier
        s16x8 aw[4];
        if (!last) {                        // W1T A-frags from L2 (384 KB resident)
            const unsigned short* wrow =
                W1T + (size_t)(w * 32 + l31) * (cT * 64) + t * 64 + lhi * 8;
            #pragma unroll
            for (int ks = 0; ks < 4; ks++) aw[ks] = *(const s16x8*)(wrow + ks * 16);
        }
        // encode MFMA: D[node][g], C-init = hc
        f32x16 d;
        #pragma unroll
        for (int reg = 0; reg < 16; reg++) d[reg] = hcr[reg];
        {
            int node = mtile * 32 + l31;
            int base = node * 64 + lhi * 8;
            int sw = (node & 7) << 3;
            #pragma unroll
            for (int ks = 0; ks < 4; ks++) {
                s16x8 a = *(const s16x8*)&sHist[(base + ks * 16) ^ sw];
                d = __builtin_amdgcn_mfma_f32_32x32x16_bf16(a, wenc[ks], d, 0, 0, 0);
            }
        }
        if (last) {
            int col = gtile * 32 + l31;
            #pragma unroll
            for (int reg = 0; reg < 16; reg++) {
                int row = mtile * 32 + (reg & 3) + 8 * (reg >> 2) + 4 * lhi;
                if (row < nn)
                    h0[(size_t)(b * cN + n0 + row) * 64 + col] = tanh_fast(d[reg]);
            }
        } else {
            int col = gtile * 32 + l31;
            #pragma unroll
            for (int reg = 0; reg < 16; reg++) {
                int row = mtile * 32 + (reg & 3) + 8 * (reg >> 2) + 4 * lhi;
                int idx = (row * 64 + col) ^ ((row & 7) << 3);
                sXe[idx] = f2bf_rtz(tanh_fast(d[reg]));
            }
            __syncthreads();   // sXe visible; all sHist(t) readers retired
            #pragma unroll
            for (int nt = 0; nt < 2; nt++) {
                int noderow = nt * 32 + l31;
                int bbase = noderow * 64 + lhi * 8;
                int swB = (noderow & 7) << 3;
                #pragma unroll
                for (int ks = 0; ks < 4; ks++) {
                    s16x8 bx = *(const s16x8*)&sXe[(bbase + ks * 16) ^ swB];
                    accm[nt] = __builtin_amdgcn_mfma_f32_32x32x16_bf16(aw[ks], bx, accm[nt], 0, 0, 0);
                }
            }
            SSTORE();          // write t+1 tile (safe: post-barrier)
            __syncthreads();   // sHist(t+1) visible for next iteration
        }
    }
    // store acc': lane holds node = nt*32+l31, hid quads
    #pragma unroll
    for (int nt = 0; nt < 2; nt++) {
        int node = nt * 32 + l31;
        if (node < nn) {
            float* ap = accbuf + (size_t)(b * cN + n0 + node) * cHID;
            #pragma unroll
            for (int q = 0; q < 4; q++) {
                int hid0 = w * 32 + q * 8 + lhi * 4;
                float4 v = make_float4(accm[nt][q * 4 + 0], accm[nt][q * 4 + 1],
                                       accm[nt][q * 4 + 2], accm[nt][q * 4 + 3]);
                *(float4*)(ap + hid0) = v;
            }
        }
    }
}

// ---------- CSR build (by destination / col) ----------
__global__ void k_count(const int* __restrict__ edges, const int* __restrict__ flag,
                        int* __restrict__ cnt_in) {
    int e = blockIdx.x * 256 + threadIdx.x;
    if (e < cE) {
        int m = *flag;
        atomicAdd(&cnt_in[edges[m * (cE + e)]], 1);
    }
}

__global__ void k_dinv(const int* __restrict__ cnt_in, float* __restrict__ dinv) {
    int n = blockIdx.x * 256 + threadIdx.x;
    if (n < cN) dinv[n] = rsqrtf((float)(cnt_in[n] + 1));   // +1 self-loop
}

// single-wave shfl scan, 4 elems/lane/iter
__global__ void k_scan(const int* __restrict__ cnt_in, int* __restrict__ rowptr) {
    int lane = threadIdx.x;   // 64 threads
    int carry = 0;
    for (int base = 0; base < cN; base += 256) {
        int i0 = base + lane * 4;
        int v0 = (i0 + 0 < cN) ? cnt_in[i0 + 0] : 0;
        int v1 = (i0 + 1 < cN) ? cnt_in[i0 + 1] : 0;
        int v2 = (i0 + 2 < cN) ? cnt_in[i0 + 2] : 0;
        int v3 = (i0 + 3 < cN) ? cnt_in[i0 + 3] : 0;
        int sum4 = v0 + v1 + v2 + v3;
        int s = sum4;
        #pragma unroll
        for (int d = 1; d < 64; d <<= 1) {
            int u = __shfl_up(s, d, 64);
            if (lane >= d) s += u;
        }
        int pre = carry + s - sum4;   // exclusive prefix for this lane's quad
        if (i0 + 0 < cN) rowptr[i0 + 0] = pre;            pre += v0;
        if (i0 + 1 < cN) rowptr[i0 + 1] = pre;            pre += v1;
        if (i0 + 2 < cN) rowptr[i0 + 2] = pre;            pre += v2;
        if (i0 + 3 < cN) rowptr[i0 + 3] = pre;
        carry += __shfl(s, 63, 64);
    }
    if (lane == 0) rowptr[cN] = carry;
}

__global__ void k_fill(const int* __restrict__ edges, const int* __restrict__ flag,
                       const int* __restrict__ rowptr, int* __restrict__ cursor,
                       int* __restrict__ csr_src) {
    int e = blockIdx.x * 256 + threadIdx.x;
    if (e < cE) {
        int m = *flag;
        int r = edges[m * e];
        int c = edges[m * (cE + e)];
        int pos = atomicAdd(&cursor[c], 1);
        csr_src[rowptr[c] + pos] = r;
    }
}

// ---------- GCN step ----------
// xfc[n][b][g] = dinv[n] * (h[b,n,:] @ W_fc)[g]
__global__ void k_fc(const float* __restrict__ h, const float* __restrict__ W_fc,
                     const float* __restrict__ dinv, float* __restrict__ xfc) {
    int n = blockIdx.x;
    int g = threadIdx.x & 63, bb = threadIdx.x >> 6;
    __shared__ float sh[4][64];
    sh[bb][g] = h[(size_t)(bb * cN + n) * 64 + g];
    __syncthreads();
    float a = 0.f;
    #pragma unroll 8
    for (int f = 0; f < 64; f++) a = fmaf(sh[bb][f], W_fc[f * 64 + g], a);
    xfc[(size_t)n * 256 + bb * 64 + g] = dinv[n] * a;
}

// hnext[b,n,:] = b_gcn + dinv[n]*(xfc[n] + sum_in xfc[s]); wave = (node, batch-pair)
__launch_bounds__(256)
__global__ void k_gather(const int* __restrict__ rowptr, const int* __restrict__ csr_src,
                         const float* __restrict__ dinv, const float* __restrict__ xfc,
                         const float* __restrict__ b_gcn, float* __restrict__ hnext) {
    int wv = threadIdx.x >> 6;
    int n = blockIdx.x * 2 + (wv >> 1);
    if (n >= cN) return;
    int bp = wv & 1;                      // batches {0,1} or {2,3}
    int g = threadIdx.x & 63;
    const float* xn = xfc + (size_t)n * 256 + bp * 128;
    float a0 = xn[g], a1 = xn[64 + g];
    int i = rowptr[n], end = rowptr[n + 1];
    int s_next = (i < end) ? csr_src[i] : 0;
    while (i < end) {
        const float* xs = xfc + (size_t)s_next * 256 + bp * 128;
        ++i;
        s_next = (i < end) ? csr_src[i] : 0;
        a0 += xs[g]; a1 += xs[64 + g];
    }
    float di = dinv[n], bg = b_gcn[g];
    hnext[(size_t)((bp * 2 + 0) * cN + n) * 64 + g] = fmaf(di, a0, bg);
    hnext[(size_t)((bp * 2 + 1) * cN + n) * 64 + g] = fmaf(di, a1, bg);
}

// ---------- head: out = relu(acc + h_fin@W1_{T-1} + b1) @ W2 + b2 ----------
__global__ void k_head(const float* __restrict__ accbuf, const float* __restrict__ hfin,
                       const float* __restrict__ W1, const float* __restrict__ b1,
                       const float* __restrict__ W2, const float* __restrict__ b2,
                       float* __restrict__ out) {
    int pair = blockIdx.x;
    int j = threadIdx.x;   // 0..127
    __shared__ float sh[64];
    __shared__ float red[128];
    if (j < 64) sh[j] = hfin[(size_t)pair * 64 + j];
    __syncthreads();
    float a = accbuf[(size_t)pair * cHID + j] + b1[j];
    const float* wp = W1 + (size_t)(cT - 1) * 64 * cHID + j;
    for (int f = 0; f < 64; f++) a = fmaf(sh[f], wp[f * cHID], a);
    a = fmaxf(a, 0.f) * W2[j];
    red[j] = a;
    __syncthreads();
    for (int s = 64; s > 0; s >>= 1) {
        if (j < s) red[j] += red[j + s];
        __syncthreads();
    }
    if (j == 0) out[pair] = red[0] + b2[0];
}

extern "C" void kernel_launch(void* const* d_in, const int* in_sizes, int n_in,
                              void* d_out, int out_size, void* d_ws, size_t ws_size,
                              hipStream_t stream) {
    const float* history = (const float*)d_in[0];
    const float* horizon = (const float*)d_in[1];
    const int*   edges   = (const int*)d_in[2];
    const float* W_enc   = (const float*)d_in[3];
    const float* W_hor   = (const float*)d_in[4];
    const float* b_enc   = (const float*)d_in[5];
    const float* W_fc    = (const float*)d_in[6];
    const float* b_gcn   = (const float*)d_in[7];
    const float* W1      = (const float*)d_in[8];
    const float* b1      = (const float*)d_in[9];
    const float* W2      = (const float*)d_in[10];
    const float* b2      = (const float*)d_in[11];
    float* out = (float*)d_out;

    float* ws = (float*)d_ws;
    float* hc     = ws;                                   // B*N*64
    float* accbuf = hc + (size_t)cB * cN * 64;            // B*N*128
    float* h0     = accbuf + (size_t)cB * cN * cHID;      // B*N*64
    float* h1     = h0 + (size_t)cB * cN * 64;            // B*N*64
    float* xfc    = h1 + (size_t)cB * cN * 64;            // N*B*64 (n-major)
    float* dinv   = xfc + (size_t)cB * cN * 64;           // N
    unsigned short* w1t = (unsigned short*)(dinv + cN);   // 128*1536 bf16
    int*   cnt_in = (int*)(w1t + (size_t)cHID * cT * 64); // N
    int*   cursor = cnt_in + cN;                          // N
    int*   rowptr = cursor + cN;                          // N+1
    int*   csr_src= rowptr + cN + 1;                      // E
    int*   cnt    = csr_src + cE;
    int*   flag   = cnt + 1;

    k_zero<<<1, 1, 0, stream>>>(cnt);
    k_detect<<<(cE + 255) / 256, 256, 0, stream>>>(edges, cnt);
    k_flag<<<1, 1, 0, stream>>>(cnt, flag);

    k_w1t<<<dim3(cT * 64 / 64, cHID / 64), 256, 0, stream>>>(W1, w1t);
    k_hc<<<(cB * cN + 3) / 4, 256, 0, stream>>>(horizon, W_hor, b_enc, hc);
    k_encode_mlp<<<dim3((cN + 63) / 64, cB), 256, 0, stream>>>(history, W_enc, hc, w1t, accbuf, h0);

    k_zero2<<<(cN + 255) / 256, 256, 0, stream>>>(cnt_in, cursor);
    k_count<<<(cE + 255) / 256, 256, 0, stream>>>(edges, flag, cnt_in);
    k_dinv<<<(cN + 255) / 256, 256, 0, stream>>>(cnt_in, dinv);
    k_scan<<<1, 64, 0, stream>>>(cnt_in, rowptr);
    k_fill<<<(cE + 255) / 256, 256, 0, stream>>>(edges, flag, rowptr, cursor, csr_src);

    float* hin = h0; float* hout = h1;
    for (int s = 0; s < cK; s++) {
        k_fc<<<cN, 256, 0, stream>>>(hin, W_fc, dinv, xfc);
        k_gather<<<(cN + 1) / 2, 256, 0, stream>>>(rowptr, csr_src, dinv, xfc, b_gcn, hout);
        float* tmp = hin; hin = hout; hout = tmp;
    }

    k_head<<<cB * cN, 128, 0, stream>>>(accbuf, hin, W1, b1, W2, b2, out);
}

// Round 6
// 468.594 us; speedup vs baseline: 1.3878x; 1.3812x over previous
//
#include <hip/hip_runtime.h>

// STGAN fused forward for MI355X. Shapes fixed per reference.
constexpr int cB = 4, cT = 24, cN = 10000, cF = 64, cE = 160000, cHID = 128, cK = 3;

typedef short s16x4 __attribute__((ext_vector_type(4)));
typedef short s16x8 __attribute__((ext_vector_type(8)));
typedef float f32x16 __attribute__((ext_vector_type(16)));

__device__ __forceinline__ unsigned short f2bf(float f) {   // RNE (one-time paths)
    union { float f; unsigned u; } c; c.f = f;
    unsigned u = c.u;
    return (unsigned short)((u + 0x7FFFu + ((u >> 16) & 1u)) >> 16);
}
__device__ __forceinline__ unsigned short f2bf_rtz(float f) {
    union { float f; unsigned u; } c; c.f = f;
    return (unsigned short)(c.u >> 16);
}
__device__ __forceinline__ unsigned asu(float f) {
    union { float f; unsigned u; } c; c.f = f; return c.u;
}

__device__ __forceinline__ float tanh_fast(float x) {
    float e = __expf(2.0f * x);
    return 1.0f - 2.0f * __builtin_amdgcn_rcpf(e + 1.0f);
}

// ---------- edge dtype detection (int32 vs int64 pushed buffer) ----------
__global__ void k_zero(int* c) { *c = 0; }

__global__ void k_detect(const int* __restrict__ edges, int* __restrict__ cnt) {
    int i = blockIdx.x * 256 + threadIdx.x;
    int z = (i < cE && edges[2 * i + 1] == 0) ? 1 : 0;
    __shared__ int sc;
    if (threadIdx.x == 0) sc = 0;
    __syncthreads();
    if (z) atomicAdd(&sc, 1);
    __syncthreads();
    if (threadIdx.x == 0 && sc) atomicAdd(cnt, sc);
}

__global__ void k_flag(const int* __restrict__ cnt, int* __restrict__ flag) {
    *flag = (*cnt > cE - 100) ? 2 : 1;
}

// zero cnt_in + cursor without a captured memset node
__global__ void k_zero2(int* __restrict__ a, int* __restrict__ b) {
    int i = blockIdx.x * 256 + threadIdx.x;
    if (i < cN) { a[i] = 0; b[i] = 0; }
}

// ---------- W1 pre-transpose: W1T[hid][gp] = bf16(W1[gp][hid]) ----------
__global__ void k_w1t(const float* __restrict__ W1, unsigned short* __restrict__ W1T) {
    __shared__ float sT[64][65];
    const int gx = blockIdx.x * 64;   // gp tile (24)
    const int hx = blockIdx.y * 64;   // hid tile (2)
    const int tid = threadIdx.x;
    #pragma unroll
    for (int r = 0; r < 4; r++) {
        int flat = tid + r * 256;             // float4 idx 0..1023
        int gp = flat >> 4, h4 = (flat & 15) * 4;
        float4 v = *(const float4*)&W1[(size_t)(gx + gp) * cHID + hx + h4];
        sT[h4 + 0][gp] = v.x; sT[h4 + 1][gp] = v.y;
        sT[h4 + 2][gp] = v.z; sT[h4 + 3][gp] = v.w;
    }
    __syncthreads();
    #pragma unroll
    for (int r = 0; r < 2; r++) {
        int flat = tid + r * 256;             // bf16x8 idx 0..511
        int h = flat >> 3, seg = flat & 7;
        s16x8 o;
        #pragma unroll
        for (int i = 0; i < 8; i++) o[i] = (short)f2bf(sT[h][seg * 8 + i]);
        *(s16x8*)&W1T[(size_t)(hx + h) * (cT * 64) + gx + seg * 8] = o;
    }
}

// ---------- hor_ctx = mean(horizon,1) @ W_hor + b_enc ----------
__global__ void k_hc(const float* __restrict__ horizon, const float* __restrict__ W_hor,
                     const float* __restrict__ b_enc, float* __restrict__ hc) {
    int g = threadIdx.x & 63;
    int sub = threadIdx.x >> 6;
    int pair = blockIdx.x * 4 + sub;          // b*N + n
    __shared__ float sm[4][64];
    bool ok = pair < cB * cN;
    float m = 0.f;
    if (ok) {
        int b = pair / cN, n = pair % cN;
        const float* hp = horizon + ((size_t)(b * 6) * cN + n) * 64 + g;
        #pragma unroll
        for (int hh = 0; hh < 6; hh++) m += hp[(size_t)hh * cN * 64];
        m *= (1.0f / 6.0f);
    }
    sm[sub][g] = m;
    __syncthreads();
    if (!ok) return;
    float a = b_enc[g];
    for (int f = 0; f < 64; f++) a = fmaf(sm[sub][f], W_hor[f * 64 + g], a);
    hc[(size_t)pair * 64 + g] = a;
}

// ---------- fused encode + MLP accumulate, bf16 MFMA ----------
// grid (157, B); 4 waves / 64-node tile; sHist double-buffered so the t+1
// register prefetch (r[4]) is stored right after the encode MFMAs -> short
// live range, no spill. sW1T staged cooperatively to LDS (proven R3 path).
__launch_bounds__(256, 2)
__global__ void k_encode_mlp(const float* __restrict__ history,
                             const float* __restrict__ W_enc,
                             const float* __restrict__ hc,
                             const unsigned short* __restrict__ W1T,
                             float* __restrict__ accbuf,
                             float* __restrict__ h0) {
    __shared__ unsigned short sHist[2][64 * 64];   // [buf][node][f], xor-swizzled, 16KB
    __shared__ unsigned short sXe[64 * 64];        // [node][g], xor-swizzled, 8KB
    __shared__ unsigned short sW1T[128 * 64];      // [hid][g], xor-swizzled, 16KB
    const int tid = threadIdx.x;
    const int lane = tid & 63;
    const int w = tid >> 6;
    const int l31 = lane & 31;
    const int lhi = lane >> 5;
    const int n0 = blockIdx.x * 64;
    const int b = blockIdx.y;
    const int nn = min(64, cN - n0);
    const int mtile = w & 1;
    const int gtile = w >> 1;

    float4 r[4];
    auto RLOAD = [&](int t) {
        const float* hsrc = history + ((size_t)(b * cT + t) * cN + n0) * 64;
        #pragma unroll
        for (int q = 0; q < 4; q++) {
            int flat = tid + q * 256;
            int node = flat >> 4, fq = flat & 15;
            r[q] = make_float4(0.f, 0.f, 0.f, 0.f);
            if (node < nn) r[q] = *(const float4*)(hsrc + node * 64 + fq * 4);
        }
    };
    auto SSTORE = [&](int buf) {
        #pragma unroll
        for (int q = 0; q < 4; q++) {
            int flat = tid + q * 256;
            int node = flat >> 4, fq = flat & 15;
            int2 p;
            p.x = (int)__builtin_amdgcn_perm(asu(r[q].y), asu(r[q].x), 0x07060302u);
            p.y = (int)__builtin_amdgcn_perm(asu(r[q].w), asu(r[q].z), 0x07060302u);
            int idx = (node * 64 + fq * 4) ^ ((node & 7) << 3);
            *(int2*)&sHist[buf][idx] = p;
        }
    };

    // W_enc B-fragments, register resident (col = gtile*32 + l31)
    s16x8 wenc[4];
    {
        int col = gtile * 32 + l31;
        #pragma unroll
        for (int ks = 0; ks < 4; ks++)
            #pragma unroll
            for (int i = 0; i < 8; i++)
                wenc[ks][i] = (short)f2bf(W_enc[(ks * 16 + lhi * 8 + i) * 64 + col]);
    }
    // hc as loop-invariant C-init
    float hcr[16];
    {
        int col = gtile * 32 + l31;
        #pragma unroll
        for (int reg = 0; reg < 16; reg++) {
            int row = mtile * 32 + (reg & 3) + 8 * (reg >> 2) + 4 * lhi;
            hcr[reg] = (row < nn) ? hc[(size_t)(b * cN + n0 + row) * 64 + col] : 0.f;
        }
    }
    f32x16 accm[2];
    #pragma unroll
    for (int nt = 0; nt < 2; nt++)
        #pragma unroll
        for (int rr = 0; rr < 16; rr++) accm[nt][rr] = 0.f;

    RLOAD(0);
    SSTORE(0);
    int cur = 0;

    for (int t = 0; t < cT; t++) {
        const bool last = (t == cT - 1);
        __syncthreads();   // sHist[cur] ready; t-1's MLP readers of sXe/sW1T done
        if (!last) {
            // stage sW1T(t) cooperatively (16 KB, coalesced 128B rows; L2/L3-hot)
            const unsigned short* wsrc = W1T + t * 64;
            #pragma unroll
            for (int q = 0; q < 4; q++) {
                int flat = tid + q * 256;       // bf16x8 idx 0..1023
                int hid = flat >> 3, seg = flat & 7;
                s16x8 vv = *(const s16x8*)(wsrc + (size_t)hid * (cT * 64) + seg * 8);
                int idx = (hid * 64 + seg * 8) ^ ((hid & 7) << 3);
                *(s16x8*)&sW1T[idx] = vv;
            }
            RLOAD(t + 1);                       // issue next-t history loads early
        }
        // encode MFMA: D[node][g], C-init = hc
        f32x16 d;
        #pragma unroll
        for (int reg = 0; reg < 16; reg++) d[reg] = hcr[reg];
        {
            int node = mtile * 32 + l31;
            int base = node * 64 + lhi * 8;
            int sw = (node & 7) << 3;
            #pragma unroll
            for (int ks = 0; ks < 4; ks++) {
                s16x8 a = *(const s16x8*)&sHist[cur][(base + ks * 16) ^ sw];
                d = __builtin_amdgcn_mfma_f32_32x32x16_bf16(a, wenc[ks], d, 0, 0, 0);
            }
        }
        if (!last) SSTORE(cur ^ 1);             // retire prefetch into other buffer
        if (last) {
            int col = gtile * 32 + l31;
            #pragma unroll
            for (int reg = 0; reg < 16; reg++) {
                int row = mtile * 32 + (reg & 3) + 8 * (reg >> 2) + 4 * lhi;
                if (row < nn)
                    h0[(size_t)(b * cN + n0 + row) * 64 + col] = tanh_fast(d[reg]);
            }
        } else {
            int col = gtile * 32 + l31;
            #pragma unroll
            for (int reg = 0; reg < 16; reg++) {
                int row = mtile * 32 + (reg & 3) + 8 * (reg >> 2) + 4 * lhi;
                int idx = (row * 64 + col) ^ ((row & 7) << 3);
                sXe[idx] = f2bf_rtz(tanh_fast(d[reg]));
            }
            __syncthreads();   // sXe + sW1T visible
            const int hidrow = w * 32 + l31;
            const int abase = hidrow * 64 + lhi * 8;
            const int swA = (hidrow & 7) << 3;
            #pragma unroll
            for (int nt = 0; nt < 2; nt++) {
                int noderow = nt * 32 + l31;
                int bbase = noderow * 64 + lhi * 8;
                int swB = (noderow & 7) << 3;
                #pragma unroll
                for (int ks = 0; ks < 4; ks++) {
                    s16x8 aw = *(const s16x8*)&sW1T[(abase + ks * 16) ^ swA];
                    s16x8 bx = *(const s16x8*)&sXe[(bbase + ks * 16) ^ swB];
                    accm[nt] = __builtin_amdgcn_mfma_f32_32x32x16_bf16(aw, bx, accm[nt], 0, 0, 0);
                }
            }
            cur ^= 1;
        }
    }
    // store acc': lane holds node = nt*32+l31, hid quads
    #pragma unroll
    for (int nt = 0; nt < 2; nt++) {
        int node = nt * 32 + l31;
        if (node < nn) {
            float* ap = accbuf + (size_t)(b * cN + n0 + node) * cHID;
            #pragma unroll
            for (int q = 0; q < 4; q++) {
                int hid0 = w * 32 + q * 8 + lhi * 4;
                float4 v = make_float4(accm[nt][q * 4 + 0], accm[nt][q * 4 + 1],
                                       accm[nt][q * 4 + 2], accm[nt][q * 4 + 3]);
                *(float4*)(ap + hid0) = v;
            }
        }
    }
}

// ---------- CSR build (by destination / col) ----------
__global__ void k_count(const int* __restrict__ edges, const int* __restrict__ flag,
                        int* __restrict__ cnt_in) {
    int e = blockIdx.x * 256 + threadIdx.x;
    if (e < cE) {
        int m = *flag;
        atomicAdd(&cnt_in[edges[m * (cE + e)]], 1);
    }
}

__global__ void k_dinv(const int* __restrict__ cnt_in, float* __restrict__ dinv) {
    int n = blockIdx.x * 256 + threadIdx.x;
    if (n < cN) dinv[n] = rsqrtf((float)(cnt_in[n] + 1));   // +1 self-loop
}

// single-wave shfl scan, 4 elems/lane/iter
__global__ void k_scan(const int* __restrict__ cnt_in, int* __restrict__ rowptr) {
    int lane = threadIdx.x;   // 64 threads
    int carry = 0;
    for (int base = 0; base < cN; base += 256) {
        int i0 = base + lane * 4;
        int v0 = (i0 + 0 < cN) ? cnt_in[i0 + 0] : 0;
        int v1 = (i0 + 1 < cN) ? cnt_in[i0 + 1] : 0;
        int v2 = (i0 + 2 < cN) ? cnt_in[i0 + 2] : 0;
        int v3 = (i0 + 3 < cN) ? cnt_in[i0 + 3] : 0;
        int sum4 = v0 + v1 + v2 + v3;
        int s = sum4;
        #pragma unroll
        for (int d = 1; d < 64; d <<= 1) {
            int u = __shfl_up(s, d, 64);
            if (lane >= d) s += u;
        }
        int pre = carry + s - sum4;   // exclusive prefix for this lane's quad
        if (i0 + 0 < cN) rowptr[i0 + 0] = pre;            pre += v0;
        if (i0 + 1 < cN) rowptr[i0 + 1] = pre;            pre += v1;
        if (i0 + 2 < cN) rowptr[i0 + 2] = pre;            pre += v2;
        if (i0 + 3 < cN) rowptr[i0 + 3] = pre;
        carry += __shfl(s, 63, 64);
    }
    if (lane == 0) rowptr[cN] = carry;
}

__global__ void k_fill(const int* __restrict__ edges, const int* __restrict__ flag,
                       const int* __restrict__ rowptr, int* __restrict__ cursor,
                       int* __restrict__ csr_src) {
    int e = blockIdx.x * 256 + threadIdx.x;
    if (e < cE) {
        int m = *flag;
        int r = edges[m * e];
        int c = edges[m * (cE + e)];
        int pos = atomicAdd(&cursor[c], 1);
        csr_src[rowptr[c] + pos] = r;
    }
}

// ---------- GCN step ----------
// xfc[n][b][g] = dinv[n] * (h[b,n,:] @ W_fc)[g]
__global__ void k_fc(const float* __restrict__ h, const float* __restrict__ W_fc,
                     const float* __restrict__ dinv, float* __restrict__ xfc) {
    int n = blockIdx.x;
    int g = threadIdx.x & 63, bb = threadIdx.x >> 6;
    __shared__ float sh[4][64];
    sh[bb][g] = h[(size_t)(bb * cN + n) * 64 + g];
    __syncthreads();
    float a = 0.f;
    #pragma unroll 8
    for (int f = 0; f < 64; f++) a = fmaf(sh[bb][f], W_fc[f * 64 + g], a);
    xfc[(size_t)n * 256 + bb * 64 + g] = dinv[n] * a;
}

// hnext[b,n,:] = b_gcn + dinv[n]*(xfc[n] + sum_in xfc[s]); wave = (node, batch-pair)
__launch_bounds__(256)
__global__ void k_gather(const int* __restrict__ rowptr, const int* __restrict__ csr_src,
                         const float* __restrict__ dinv, const float* __restrict__ xfc,
                         const float* __restrict__ b_gcn, float* __restrict__ hnext) {
    int wv = threadIdx.x >> 6;
    int n = blockIdx.x * 2 + (wv >> 1);
    if (n >= cN) return;
    int bp = wv & 1;                      // batches {0,1} or {2,3}
    int g = threadIdx.x & 63;
    const float* xn = xfc + (size_t)n * 256 + bp * 128;
    float a0 = xn[g], a1 = xn[64 + g];
    int i = rowptr[n], end = rowptr[n + 1];
    int s_next = (i < end) ? csr_src[i] : 0;
    while (i < end) {
        const float* xs = xfc + (size_t)s_next * 256 + bp * 128;
        ++i;
        s_next = (i < end) ? csr_src[i] : 0;
        a0 += xs[g]; a1 += xs[64 + g];
    }
    float di = dinv[n], bg = b_gcn[g];
    hnext[(size_t)((bp * 2 + 0) * cN + n) * 64 + g] = fmaf(di, a0, bg);
    hnext[(size_t)((bp * 2 + 1) * cN + n) * 64 + g] = fmaf(di, a1, bg);
}

// ---------- head: out = relu(acc + h_fin@W1_{T-1} + b1) @ W2 + b2 ----------
__global__ void k_head(const float* __restrict__ accbuf, const float* __restrict__ hfin,
                       const float* __restrict__ W1, const float* __restrict__ b1,
                       const float* __restrict__ W2, const float* __restrict__ b2,
                       float* __restrict__ out) {
    int pair = blockIdx.x;
    int j = threadIdx.x;   // 0..127
    __shared__ float sh[64];
    __shared__ float red[128];
    if (j < 64) sh[j] = hfin[(size_t)pair * 64 + j];
    __syncthreads();
    float a = accbuf[(size_t)pair * cHID + j] + b1[j];
    const float* wp = W1 + (size_t)(cT - 1) * 64 * cHID + j;
    for (int f = 0; f < 64; f++) a = fmaf(sh[f], wp[f * cHID], a);
    a = fmaxf(a, 0.f) * W2[j];
    red[j] = a;
    __syncthreads();
    for (int s = 64; s > 0; s >>= 1) {
        if (j < s) red[j] += red[j + s];
        __syncthreads();
    }
    if (j == 0) out[pair] = red[0] + b2[0];
}

extern "C" void kernel_launch(void* const* d_in, const int* in_sizes, int n_in,
                              void* d_out, int out_size, void* d_ws, size_t ws_size,
                              hipStream_t stream) {
    const float* history = (const float*)d_in[0];
    const float* horizon = (const float*)d_in[1];
    const int*   edges   = (const int*)d_in[2];
    const float* W_enc   = (const float*)d_in[3];
    const float* W_hor   = (const float*)d_in[4];
    const float* b_enc   = (const float*)d_in[5];
    const float* W_fc    = (const float*)d_in[6];
    const float* b_gcn   = (const float*)d_in[7];
    const float* W1      = (const float*)d_in[8];
    const float* b1      = (const float*)d_in[9];
    const float* W2      = (const float*)d_in[10];
    const float* b2      = (const float*)d_in[11];
    float* out = (float*)d_out;

    float* ws = (float*)d_ws;
    float* hc     = ws;                                   // B*N*64
    float* accbuf = hc + (size_t)cB * cN * 64;            // B*N*128
    float* h0     = accbuf + (size_t)cB * cN * cHID;      // B*N*64
    float* h1     = h0 + (size_t)cB * cN * 64;            // B*N*64
    float* xfc    = h1 + (size_t)cB * cN * 64;            // N*B*64 (n-major)
    float* dinv   = xfc + (size_t)cB * cN * 64;           // N
    unsigned short* w1t = (unsigned short*)(dinv + cN);   // 128*1536 bf16
    int*   cnt_in = (int*)(w1t + (size_t)cHID * cT * 64); // N
    int*   cursor = cnt_in + cN;                          // N
    int*   rowptr = cursor + cN;                          // N+1
    int*   csr_src= rowptr + cN + 1;                      // E
    int*   cnt    = csr_src + cE;
    int*   flag   = cnt + 1;

    k_zero<<<1, 1, 0, stream>>>(cnt);
    k_detect<<<(cE + 255) / 256, 256, 0, stream>>>(edges, cnt);
    k_flag<<<1, 1, 0, stream>>>(cnt, flag);

    k_w1t<<<dim3(cT * 64 / 64, cHID / 64), 256, 0, stream>>>(W1, w1t);
    k_hc<<<(cB * cN + 3) / 4, 256, 0, stream>>>(horizon, W_hor, b_enc, hc);
    k_encode_mlp<<<dim3((cN + 63) / 64, cB), 256, 0, stream>>>(history, W_enc, hc, w1t, accbuf, h0);

    k_zero2<<<(cN + 255) / 256, 256, 0, stream>>>(cnt_in, cursor);
    k_count<<<(cE + 255) / 256, 256, 0, stream>>>(edges, flag, cnt_in);
    k_dinv<<<(cN + 255) / 256, 256, 0, stream>>>(cnt_in, dinv);
    k_scan<<<1, 64, 0, stream>>>(cnt_in, rowptr);
    k_fill<<<(cE + 255) / 256, 256, 0, stream>>>(edges, flag, rowptr, cursor, csr_src);

    float* hin = h0; float* hout = h1;
    for (int s = 0; s < cK; s++) {
        k_fc<<<cN, 256, 0, stream>>>(hin, W_fc, dinv, xfc);
        k_gather<<<(cN + 1) / 2, 256, 0, stream>>>(rowptr, csr_src, dinv, xfc, b_gcn, hout);
        float* tmp = hin; hin = hout; hout = tmp;
    }

    k_head<<<cB * cN, 128, 0, stream>>>(accbuf, hin, W1, b1, W2, b2, out);
}

// Round 7
// 407.218 us; speedup vs baseline: 1.5970x; 1.1507x over previous
//
#include <hip/hip_runtime.h>

// STGAN fused forward for MI355X. Shapes fixed per reference.
constexpr int cB = 4, cT = 24, cN = 10000, cF = 64, cE = 160000, cHID = 128, cK = 3;

typedef short s16x4 __attribute__((ext_vector_type(4)));
typedef short s16x8 __attribute__((ext_vector_type(8)));
typedef float f32x16 __attribute__((ext_vector_type(16)));

__device__ __forceinline__ unsigned short f2bf(float f) {   // RNE (one-time paths)
    union { float f; unsigned u; } c; c.f = f;
    unsigned u = c.u;
    return (unsigned short)((u + 0x7FFFu + ((u >> 16) & 1u)) >> 16);
}
__device__ __forceinline__ unsigned short f2bf_rtz(float f) {
    union { float f; unsigned u; } c; c.f = f;
    return (unsigned short)(c.u >> 16);
}
__device__ __forceinline__ unsigned asu(float f) {
    union { float f; unsigned u; } c; c.f = f; return c.u;
}

__device__ __forceinline__ float tanh_fast(float x) {
    float e = __expf(2.0f * x);
    return 1.0f - 2.0f * __builtin_amdgcn_rcpf(e + 1.0f);
}

// ---------- edge dtype detection (int32 vs int64 pushed buffer) ----------
__global__ void k_zero(int* c) { *c = 0; }

__global__ void k_detect(const int* __restrict__ edges, int* __restrict__ cnt) {
    int i = blockIdx.x * 256 + threadIdx.x;
    int z = (i < cE && edges[2 * i + 1] == 0) ? 1 : 0;
    __shared__ int sc;
    if (threadIdx.x == 0) sc = 0;
    __syncthreads();
    if (z) atomicAdd(&sc, 1);
    __syncthreads();
    if (threadIdx.x == 0 && sc) atomicAdd(cnt, sc);
}

__global__ void k_flag(const int* __restrict__ cnt, int* __restrict__ flag) {
    *flag = (*cnt > cE - 100) ? 2 : 1;
}

// zero cnt_in + cursor without a captured memset node
__global__ void k_zero2(int* __restrict__ a, int* __restrict__ b) {
    int i = blockIdx.x * 256 + threadIdx.x;
    if (i < cN) { a[i] = 0; b[i] = 0; }
}

// ---------- W1 pre-transpose: W1T[hid][gp] = bf16(W1[gp][hid]) ----------
__global__ void k_w1t(const float* __restrict__ W1, unsigned short* __restrict__ W1T) {
    __shared__ float sT[64][65];
    const int gx = blockIdx.x * 64;   // gp tile (24)
    const int hx = blockIdx.y * 64;   // hid tile (2)
    const int tid = threadIdx.x;
    #pragma unroll
    for (int r = 0; r < 4; r++) {
        int flat = tid + r * 256;             // float4 idx 0..1023
        int gp = flat >> 4, h4 = (flat & 15) * 4;
        float4 v = *(const float4*)&W1[(size_t)(gx + gp) * cHID + hx + h4];
        sT[h4 + 0][gp] = v.x; sT[h4 + 1][gp] = v.y;
        sT[h4 + 2][gp] = v.z; sT[h4 + 3][gp] = v.w;
    }
    __syncthreads();
    #pragma unroll
    for (int r = 0; r < 2; r++) {
        int flat = tid + r * 256;             // bf16x8 idx 0..511
        int h = flat >> 3, seg = flat & 7;
        s16x8 o;
        #pragma unroll
        for (int i = 0; i < 8; i++) o[i] = (short)f2bf(sT[h][seg * 8 + i]);
        *(s16x8*)&W1T[(size_t)(hx + h) * (cT * 64) + gx + seg * 8] = o;
    }
}

// ---------- fused horizon-mean + encode + MLP accumulate, bf16 MFMA ----------
// grid (313, B); 2 waves / 32-node tile; LDS 12 KB. Wave w: encode cols
// g = w*32.., MLP hid rows w*64.. . hor_ctx computed in-kernel via one extra
// MFMA pass (C-init = b_enc). sHist double-buffered; W1T frags direct from L2.
__launch_bounds__(128, 2)
__global__ void k_encode_mlp(const float* __restrict__ history,
                             const float* __restrict__ horizon,
                             const float* __restrict__ W_enc,
                             const float* __restrict__ W_hor,
                             const float* __restrict__ b_enc,
                             const unsigned short* __restrict__ W1T,
                             float* __restrict__ accbuf,
                             float* __restrict__ h0) {
    __shared__ unsigned short sHist[2][32 * 64];   // [buf][node][f], swizzled, 8KB
    __shared__ unsigned short sXe[32 * 64];        // [node][g], swizzled, 4KB
    const int tid = threadIdx.x;    // 0..127
    const int lane = tid & 63;
    const int w = tid >> 6;         // 0..1
    const int l31 = lane & 31;
    const int lhi = lane >> 5;
    const int n0 = blockIdx.x * 32;
    const int b = blockIdx.y;
    const int nn = min(32, cN - n0);
    const int col = w * 32 + l31;   // encode output column (g)

    float4 r[4];
    auto RLOAD = [&](int t) {
        const float* hsrc = history + ((size_t)(b * cT + t) * cN + n0) * 64;
        #pragma unroll
        for (int q = 0; q < 4; q++) {
            int flat = tid + q * 128;       // float4 idx 0..511
            int node = flat >> 4, fq = flat & 15;
            r[q] = make_float4(0.f, 0.f, 0.f, 0.f);
            if (node < nn) r[q] = *(const float4*)(hsrc + node * 64 + fq * 4);
        }
    };
    auto SSTORE = [&](int buf) {
        #pragma unroll
        for (int q = 0; q < 4; q++) {
            int flat = tid + q * 128;
            int node = flat >> 4, fq = flat & 15;
            int2 p;
            p.x = (int)__builtin_amdgcn_perm(asu(r[q].y), asu(r[q].x), 0x07060302u);
            p.y = (int)__builtin_amdgcn_perm(asu(r[q].w), asu(r[q].z), 0x07060302u);
            int idx = (node * 64 + fq * 4) ^ ((node & 7) << 3);
            *(int2*)&sHist[buf][idx] = p;
        }
    };

    // ---- stage horizon mean tile into sHist[1] (bf16, swizzled)
    #pragma unroll
    for (int q = 0; q < 4; q++) {
        int flat = tid + q * 128;
        int node = flat >> 4, fq = flat & 15;
        float4 m = make_float4(0.f, 0.f, 0.f, 0.f);
        if (node < nn) {
            const float* hp = horizon + ((size_t)(b * 6) * cN + (n0 + node)) * 64 + fq * 4;
            #pragma unroll
            for (int hh = 0; hh < 6; hh++) {
                float4 v = *(const float4*)(hp + (size_t)hh * cN * 64);
                m.x += v.x; m.y += v.y; m.z += v.z; m.w += v.w;
            }
            m.x *= (1.f / 6.f); m.y *= (1.f / 6.f);
            m.z *= (1.f / 6.f); m.w *= (1.f / 6.f);
        }
        int2 p;
        p.x = (int)__builtin_amdgcn_perm(asu(m.y), asu(m.x), 0x07060302u);
        p.y = (int)__builtin_amdgcn_perm(asu(m.w), asu(m.z), 0x07060302u);
        int idx = (node * 64 + fq * 4) ^ ((node & 7) << 3);
        *(int2*)&sHist[1][idx] = p;
    }

    // W_enc B-fragments, register resident
    s16x8 wenc[4];
    #pragma unroll
    for (int ks = 0; ks < 4; ks++)
        #pragma unroll
        for (int i = 0; i < 8; i++)
            wenc[ks][i] = (short)f2bf(W_enc[(ks * 16 + lhi * 8 + i) * 64 + col]);

    __syncthreads();   // mean tile visible

    // ---- hor_ctx: hcr = mean @ W_hor + b_enc  (D[node][g], C-init = b_enc)
    float hcr[16];
    {
        s16x8 whor[4];
        #pragma unroll
        for (int ks = 0; ks < 4; ks++)
            #pragma unroll
            for (int i = 0; i < 8; i++)
                whor[ks][i] = (short)f2bf(W_hor[(ks * 16 + lhi * 8 + i) * 64 + col]);
        float be = b_enc[col];
        f32x16 d;
        #pragma unroll
        for (int reg = 0; reg < 16; reg++) d[reg] = be;
        int base = l31 * 64 + lhi * 8;
        int sw = (l31 & 7) << 3;
        #pragma unroll
        for (int ks = 0; ks < 4; ks++) {
            s16x8 a = *(const s16x8*)&sHist[1][(base + ks * 16) ^ sw];
            d = __builtin_amdgcn_mfma_f32_32x32x16_bf16(a, whor[ks], d, 0, 0, 0);
        }
        #pragma unroll
        for (int reg = 0; reg < 16; reg++) hcr[reg] = d[reg];
    }

    f32x16 accm[2];
    #pragma unroll
    for (int ht = 0; ht < 2; ht++)
        #pragma unroll
        for (int rr = 0; rr < 16; rr++) accm[ht][rr] = 0.f;

    RLOAD(0);
    SSTORE(0);          // buf 0; mean lives in buf 1, overwritten only after t=0 barrier+MFMA
    int cur = 0;

    for (int t = 0; t < cT; t++) {
        const bool last = (t == cT - 1);
        __syncthreads();   // sHist[cur] visible; prev iter's sXe readers done
        if (!last) RLOAD(t + 1);
        // encode MFMA: D[node][g], C-init = hcr
        f32x16 d;
        #pragma unroll
        for (int reg = 0; reg < 16; reg++) d[reg] = hcr[reg];
        {
            int base = l31 * 64 + lhi * 8;
            int sw = (l31 & 7) << 3;
            #pragma unroll
            for (int ks = 0; ks < 4; ks++) {
                s16x8 a = *(const s16x8*)&sHist[cur][(base + ks * 16) ^ sw];
                d = __builtin_amdgcn_mfma_f32_32x32x16_bf16(a, wenc[ks], d, 0, 0, 0);
            }
        }
        if (!last) SSTORE(cur ^ 1);     // retire prefetch; short r live range
        if (last) {
            #pragma unroll
            for (int reg = 0; reg < 16; reg++) {
                int row = (reg & 3) + 8 * (reg >> 2) + 4 * lhi;
                if (row < nn)
                    h0[(size_t)(b * cN + n0 + row) * 64 + col] = tanh_fast(d[reg]);
            }
        } else {
            #pragma unroll
            for (int reg = 0; reg < 16; reg++) {
                int row = (reg & 3) + 8 * (reg >> 2) + 4 * lhi;
                int idx = (row * 64 + col) ^ ((row & 7) << 3);
                sXe[idx] = f2bf_rtz(tanh_fast(d[reg]));
            }
            __syncthreads();   // sXe visible
            // MLP: wave w owns hid rows w*64 .. w*64+63 (two 32-row tiles)
            int bbase = l31 * 64 + lhi * 8;
            int swB = (l31 & 7) << 3;
            #pragma unroll
            for (int ht = 0; ht < 2; ht++) {
                const unsigned short* wrow =
                    W1T + (size_t)(w * 64 + ht * 32 + l31) * (cT * 64) + t * 64 + lhi * 8;
                #pragma unroll
                for (int ks = 0; ks < 4; ks++) {
                    s16x8 aw = *(const s16x8*)(wrow + ks * 16);
                    s16x8 bx = *(const s16x8*)&sXe[(bbase + ks * 16) ^ swB];
                    accm[ht] = __builtin_amdgcn_mfma_f32_32x32x16_bf16(aw, bx, accm[ht], 0, 0, 0);
                }
            }
            cur ^= 1;
        }
    }
    // store acc': lane holds node = l31 (col), hid rows per reg
    int node = l31;
    if (node < nn) {
        float* ap = accbuf + (size_t)(b * cN + n0 + node) * cHID;
        #pragma unroll
        for (int ht = 0; ht < 2; ht++) {
            #pragma unroll
            for (int q = 0; q < 4; q++) {
                int hid0 = w * 64 + ht * 32 + q * 8 + lhi * 4;
                float4 v = make_float4(accm[ht][q * 4 + 0], accm[ht][q * 4 + 1],
                                       accm[ht][q * 4 + 2], accm[ht][q * 4 + 3]);
                *(float4*)(ap + hid0) = v;
            }
        }
    }
}

// ---------- CSR build (by destination / col) ----------
__global__ void k_count(const int* __restrict__ edges, const int* __restrict__ flag,
                        int* __restrict__ cnt_in) {
    int e = blockIdx.x * 256 + threadIdx.x;
    if (e < cE) {
        int m = *flag;
        atomicAdd(&cnt_in[edges[m * (cE + e)]], 1);
    }
}

__global__ void k_dinv(const int* __restrict__ cnt_in, float* __restrict__ dinv) {
    int n = blockIdx.x * 256 + threadIdx.x;
    if (n < cN) dinv[n] = rsqrtf((float)(cnt_in[n] + 1));   // +1 self-loop
}

// single-wave shfl scan, 4 elems/lane/iter
__global__ void k_scan(const int* __restrict__ cnt_in, int* __restrict__ rowptr) {
    int lane = threadIdx.x;   // 64 threads
    int carry = 0;
    for (int base = 0; base < cN; base += 256) {
        int i0 = base + lane * 4;
        int v0 = (i0 + 0 < cN) ? cnt_in[i0 + 0] : 0;
        int v1 = (i0 + 1 < cN) ? cnt_in[i0 + 1] : 0;
        int v2 = (i0 + 2 < cN) ? cnt_in[i0 + 2] : 0;
        int v3 = (i0 + 3 < cN) ? cnt_in[i0 + 3] : 0;
        int sum4 = v0 + v1 + v2 + v3;
        int s = sum4;
        #pragma unroll
        for (int d = 1; d < 64; d <<= 1) {
            int u = __shfl_up(s, d, 64);
            if (lane >= d) s += u;
        }
        int pre = carry + s - sum4;   // exclusive prefix for this lane's quad
        if (i0 + 0 < cN) rowptr[i0 + 0] = pre;            pre += v0;
        if (i0 + 1 < cN) rowptr[i0 + 1] = pre;            pre += v1;
        if (i0 + 2 < cN) rowptr[i0 + 2] = pre;            pre += v2;
        if (i0 + 3 < cN) rowptr[i0 + 3] = pre;
        carry += __shfl(s, 63, 64);
    }
    if (lane == 0) rowptr[cN] = carry;
}

__global__ void k_fill(const int* __restrict__ edges, const int* __restrict__ flag,
                       const int* __restrict__ rowptr, int* __restrict__ cursor,
                       int* __restrict__ csr_src) {
    int e = blockIdx.x * 256 + threadIdx.x;
    if (e < cE) {
        int m = *flag;
        int r = edges[m * e];
        int c = edges[m * (cE + e)];
        int pos = atomicAdd(&cursor[c], 1);
        csr_src[rowptr[c] + pos] = r;
    }
}

// ---------- GCN step ----------
// xfc[n][b][g] = dinv[n] * (h[b,n,:] @ W_fc)[g]
__global__ void k_fc(const float* __restrict__ h, const float* __restrict__ W_fc,
                     const float* __restrict__ dinv, float* __restrict__ xfc) {
    int n = blockIdx.x;
    int g = threadIdx.x & 63, bb = threadIdx.x >> 6;
    __shared__ float sh[4][64];
    sh[bb][g] = h[(size_t)(bb * cN + n) * 64 + g];
    __syncthreads();
    float a = 0.f;
    #pragma unroll 8
    for (int f = 0; f < 64; f++) a = fmaf(sh[bb][f], W_fc[f * 64 + g], a);
    xfc[(size_t)n * 256 + bb * 64 + g] = dinv[n] * a;
}

// hnext[b,n,:] = b_gcn + dinv[n]*(xfc[n] + sum_in xfc[s]); wave = (node, batch-pair)
__launch_bounds__(256)
__global__ void k_gather(const int* __restrict__ rowptr, const int* __restrict__ csr_src,
                         const float* __restrict__ dinv, const float* __restrict__ xfc,
                         const float* __restrict__ b_gcn, float* __restrict__ hnext) {
    int wv = threadIdx.x >> 6;
    int n = blockIdx.x * 2 + (wv >> 1);
    if (n >= cN) return;
    int bp = wv & 1;                      // batches {0,1} or {2,3}
    int g = threadIdx.x & 63;
    const float* xn = xfc + (size_t)n * 256 + bp * 128;
    float a0 = xn[g], a1 = xn[64 + g];
    int i = rowptr[n], end = rowptr[n + 1];
    int s_next = (i < end) ? csr_src[i] : 0;
    while (i < end) {
        const float* xs = xfc + (size_t)s_next * 256 + bp * 128;
        ++i;
        s_next = (i < end) ? csr_src[i] : 0;
        a0 += xs[g]; a1 += xs[64 + g];
    }
    float di = dinv[n], bg = b_gcn[g];
    hnext[(size_t)((bp * 2 + 0) * cN + n) * 64 + g] = fmaf(di, a0, bg);
    hnext[(size_t)((bp * 2 + 1) * cN + n) * 64 + g] = fmaf(di, a1, bg);
}

// ---------- head: out = relu(acc + h_fin@W1_{T-1} + b1) @ W2 + b2 ----------
__global__ void k_head(const float* __restrict__ accbuf, const float* __restrict__ hfin,
                       const float* __restrict__ W1, const float* __restrict__ b1,
                       const float* __restrict__ W2, const float* __restrict__ b2,
                       float* __restrict__ out) {
    int pair = blockIdx.x;
    int j = threadIdx.x;   // 0..127
    __shared__ float sh[64];
    __shared__ float red[128];
    if (j < 64) sh[j] = hfin[(size_t)pair * 64 + j];
    __syncthreads();
    float a = accbuf[(size_t)pair * cHID + j] + b1[j];
    const float* wp = W1 + (size_t)(cT - 1) * 64 * cHID + j;
    for (int f = 0; f < 64; f++) a = fmaf(sh[f], wp[f * cHID], a);
    a = fmaxf(a, 0.f) * W2[j];
    red[j] = a;
    __syncthreads();
    for (int s = 64; s > 0; s >>= 1) {
        if (j < s) red[j] += red[j + s];
        __syncthreads();
    }
    if (j == 0) out[pair] = red[0] + b2[0];
}

extern "C" void kernel_launch(void* const* d_in, const int* in_sizes, int n_in,
                              void* d_out, int out_size, void* d_ws, size_t ws_size,
                              hipStream_t stream) {
    const float* history = (const float*)d_in[0];
    const float* horizon = (const float*)d_in[1];
    const int*   edges   = (const int*)d_in[2];
    const float* W_enc   = (const float*)d_in[3];
    const float* W_hor   = (const float*)d_in[4];
    const float* b_enc   = (const float*)d_in[5];
    const float* W_fc    = (const float*)d_in[6];
    const float* b_gcn   = (const float*)d_in[7];
    const float* W1      = (const float*)d_in[8];
    const float* b1      = (const float*)d_in[9];
    const float* W2      = (const float*)d_in[10];
    const float* b2      = (const float*)d_in[11];
    float* out = (float*)d_out;

    float* ws = (float*)d_ws;
    float* accbuf = ws;                                   // B*N*128
    float* h0     = accbuf + (size_t)cB * cN * cHID;      // B*N*64
    float* h1     = h0 + (size_t)cB * cN * 64;            // B*N*64
    float* xfc    = h1 + (size_t)cB * cN * 64;            // N*B*64 (n-major)
    float* dinv   = xfc + (size_t)cB * cN * 64;           // N
    unsigned short* w1t = (unsigned short*)(dinv + cN);   // 128*1536 bf16
    int*   cnt_in = (int*)(w1t + (size_t)cHID * cT * 64); // N
    int*   cursor = cnt_in + cN;                          // N
    int*   rowptr = cursor + cN;                          // N+1
    int*   csr_src= rowptr + cN + 1;                      // E
    int*   cnt    = csr_src + cE;
    int*   flag   = cnt + 1;

    k_zero<<<1, 1, 0, stream>>>(cnt);
    k_detect<<<(cE + 255) / 256, 256, 0, stream>>>(edges, cnt);
    k_flag<<<1, 1, 0, stream>>>(cnt, flag);

    k_w1t<<<dim3(cT * 64 / 64, cHID / 64), 256, 0, stream>>>(W1, w1t);
    k_encode_mlp<<<dim3((cN + 31) / 32, cB), 128, 0, stream>>>(history, horizon, W_enc, W_hor,
                                                               b_enc, w1t, accbuf, h0);

    k_zero2<<<(cN + 255) / 256, 256, 0, stream>>>(cnt_in, cursor);
    k_count<<<(cE + 255) / 256, 256, 0, stream>>>(edges, flag, cnt_in);
    k_dinv<<<(cN + 255) / 256, 256, 0, stream>>>(cnt_in, dinv);
    k_scan<<<1, 64, 0, stream>>>(cnt_in, rowptr);
    k_fill<<<(cE + 255) / 256, 256, 0, stream>>>(edges, flag, rowptr, cursor, csr_src);

    float* hin = h0; float* hout = h1;
    for (int s = 0; s < cK; s++) {
        k_fc<<<cN, 256, 0, stream>>>(hin, W_fc, dinv, xfc);
        k_gather<<<(cN + 1) / 2, 256, 0, stream>>>(rowptr, csr_src, dinv, xfc, b_gcn, hout);
        float* tmp = hin; hin = hout; hout = tmp;
    }

    k_head<<<cB * cN, 128, 0, stream>>>(accbuf, hin, W1, b1, W2, b2, out);
}